// Round 1
// baseline (7645.818 us; speedup 1.0000x reference)
//
#include <hip/hip_runtime.h>

// ---------------------------------------------------------------------------
// Persistent fused 2-layer LSTM + FC for MI355X.
//  - 256 WGs x 256 threads (1 per CU), 4 independent batch-groups of 16.
//  - Layers pipelined: global step s: L0 computes t=s, L1 computes t=s-1.
//  - Weights live in VGPRs as fp16 MFMA A-fragments (gathered once).
//  - h exchanged via agent-scope atomics (coherent across XCDs, no fences).
// ---------------------------------------------------------------------------

#define H      512
#define T_SEQ  1024
#define DIN    64
#define STEPS  1025

typedef _Float16 f16x8 __attribute__((ext_vector_type(8)));
typedef float    f32x4 __attribute__((ext_vector_type(4)));

#define H0_OFF_U32 0
#define H1_OFF_U32 32768
#define FL_OFF_U32 65536
#define WS_BYTES   (65536 * 4 + 1024)

__device__ __forceinline__ unsigned ld_u32(const unsigned* p) {
  return __hip_atomic_load((unsigned*)p, __ATOMIC_RELAXED, __HIP_MEMORY_SCOPE_AGENT);
}
__device__ __forceinline__ void st_u32(unsigned* p, unsigned v) {
  __hip_atomic_store(p, v, __ATOMIC_RELAXED, __HIP_MEMORY_SCOPE_AGENT);
}
__device__ __forceinline__ f16x8 pk8(float4 a, float4 b) {
  f16x8 r;
  r[0] = (_Float16)a.x; r[1] = (_Float16)a.y; r[2] = (_Float16)a.z; r[3] = (_Float16)a.w;
  r[4] = (_Float16)b.x; r[5] = (_Float16)b.y; r[6] = (_Float16)b.z; r[7] = (_Float16)b.w;
  return r;
}
__device__ __forceinline__ f16x8 cvt8(const float* p) {
  return pk8(*(const float4*)p, *(const float4*)(p + 4));
}
__device__ __forceinline__ f32x4 mfma16(f16x8 a, f16x8 b, f32x4 c) {
  return __builtin_amdgcn_mfma_f32_16x16x32_f16(a, b, c, 0, 0, 0);
}
__device__ __forceinline__ float rcpf_(float x) {
#if __has_builtin(__builtin_amdgcn_rcpf)
  return __builtin_amdgcn_rcpf(x);
#else
  return 1.0f / x;
#endif
}
__device__ __forceinline__ float sigm(float x) {
  x = fminf(fmaxf(x, -30.f), 30.f);
  return rcpf_(1.f + __expf(-x));
}
__device__ __forceinline__ float tanhx(float x) {
  x = fminf(fmaxf(x, -15.f), 15.f);
  float e = __expf(2.f * x);
  return (e - 1.f) * rcpf_(e + 1.f);
}

__global__ __launch_bounds__(256, 1)
void lstm_fused(const float* __restrict__ x,
                const float* __restrict__ Wih0, const float* __restrict__ Whh0,
                const float* __restrict__ bih0, const float* __restrict__ bhh0,
                const float* __restrict__ Wih1, const float* __restrict__ Whh1,
                const float* __restrict__ bih1, const float* __restrict__ bhh1,
                const float* __restrict__ fcw,  const float* __restrict__ fcb,
                float* __restrict__ out, unsigned* __restrict__ ws)
{
  // LDS: two staged h tiles [16 batch][512+8pad] fp16 (u32 view: 260/row)
  __shared__ unsigned sH[2 * 16 * 260];

  const int tid   = threadIdx.x;
  const int wid   = blockIdx.x;
  const int g     = wid >> 6;          // batch group 0..3
  const int w     = wid & 63;          // WG within group
  const int wave  = tid >> 6;
  const int lane  = tid & 63;
  const int layer = wave >> 1;         // waves 0,1 -> layer0 ; 2,3 -> layer1
  const int hb    = w * 8 + (wave & 1) * 4;  // hidden base of this wave (4 units)
  const int bcol  = lane & 15;         // batch-in-group (MFMA N col)
  const int kgrp  = lane >> 4;

  unsigned* h0g = ws + H0_OFF_U32 + g * 8192;   // [2 slots][16][256] u32
  unsigned* h1g = ws + H1_OFF_U32 + g * 8192;
  unsigned* flg = ws + FL_OFF_U32 + g * 64;

  // ---- gather resident W fragments (A operand; M rows = i,f,g,o interleaved
  //      per hidden unit so C/D lanes own one (hidden,batch) with 4 gate regs)
  const int src_m = lane & 15;
  const int grow  = (src_m & 3) * H + hb + (src_m >> 2);  // PyTorch gate-row
  f16x8 wA[32];
  if (layer == 0) {
    #pragma unroll
    for (int ks = 0; ks < 18; ++ks) {            // K = 64(x) + 512(h0) = 576
      int kk = ks * 32 + kgrp * 8;
      const float* p = (kk < DIN) ? (Wih0 + (size_t)grow * DIN + kk)
                                  : (Whh0 + (size_t)grow * H + (kk - DIN));
      wA[ks] = cvt8(p);
    }
  } else {
    #pragma unroll
    for (int ks = 0; ks < 32; ++ks) {            // K = 512(h0) + 512(h1) = 1024
      int kk = ks * 32 + kgrp * 8;
      const float* p = (kk < H) ? (Wih1 + (size_t)grow * H + kk)
                                : (Whh1 + (size_t)grow * H + (kk - H));
      wA[ks] = cvt8(p);
    }
  }
  const int hown = hb + kgrp;                    // hidden unit this lane owns
  float bias[4];
  {
    const float* bi = layer ? bih1 : bih0;
    const float* bh = layer ? bhh1 : bhh0;
    #pragma unroll
    for (int r = 0; r < 4; ++r) { int rr = r * H + hown; bias[r] = bi[rr] + bh[rr]; }
  }

  float c = 0.f;
  unsigned spins = 0;
  const int rowb = bcol * 1040 + kgrp * 16;      // LDS byte offset of B-frag row

  for (int s = 0; s < STEPS; ++s) {
    // x prefetch (raw; converted after poll so loads overlap the wait)
    float4 xr0 = {0,0,0,0}, xr1 = xr0, xr2 = xr0, xr3 = xr0;
    if (layer == 0) {
      int t = (s < T_SEQ) ? s : (T_SEQ - 1);
      const float* xp = x + ((size_t)((g * 16 + bcol) * T_SEQ + t)) * DIN + kgrp * 8;
      xr0 = *(const float4*)xp;        xr1 = *(const float4*)(xp + 4);
      xr2 = *(const float4*)(xp + 32); xr3 = *(const float4*)(xp + 36);
    }
    // wait for step s-1 of all 64 producers in this group
    if (s > 0) {
      unsigned tgt = (unsigned)s;
      for (;;) {
        unsigned fl = ld_u32(flg + lane);        // each lane polls one flag
        if (__all(fl >= tgt)) break;
        if (++spins > 1000000u) break;           // bounded anti-hang guard
        __builtin_amdgcn_s_sleep(2);
      }
      asm volatile("" ::: "memory");
    }
    // stage h0/h1 of step s-1 (agent atomics bypass stale L1/L2 across XCDs)
    {
      const int slot = (s - 1) & 1;              // s=0 reads zeroed slot 1
      const unsigned* s0 = h0g + slot * 4096;
      const unsigned* s1 = h1g + slot * 4096;
      #pragma unroll
      for (int it = 0; it < 16; ++it) {
        int i = tid + it * 256;
        int b = i >> 8, cc = i & 255;
        unsigned v0 = ld_u32(s0 + i);
        unsigned v1 = ld_u32(s1 + i);
        sH[b * 260 + cc]        = v0;
        sH[4160 + b * 260 + cc] = v1;
      }
    }
    __syncthreads();

    const bool active = layer ? (s > 0) : (s < T_SEQ);
    float hval = 0.f;
    if (active) {
      f32x4 acc[4] = {{0,0,0,0},{0,0,0,0},{0,0,0,0},{0,0,0,0}};
      const char* b0 = (const char*)sH;
      const char* b1 = (const char*)sH + 16640;
      if (layer == 0) {
        acc[0] = mfma16(wA[0], pk8(xr0, xr1), acc[0]);
        acc[1] = mfma16(wA[1], pk8(xr2, xr3), acc[1]);
        #pragma unroll
        for (int ks = 2; ks < 18; ++ks) {
          f16x8 bf = *(const f16x8*)(b0 + rowb + ks * 64 - 128);
          acc[ks & 3] = mfma16(wA[ks], bf, acc[ks & 3]);
        }
      } else {
        #pragma unroll
        for (int ks = 0; ks < 16; ++ks) {
          f16x8 bf = *(const f16x8*)(b0 + rowb + ks * 64);
          acc[ks & 3] = mfma16(wA[ks], bf, acc[ks & 3]);
        }
        #pragma unroll
        for (int ks = 16; ks < 32; ++ks) {
          f16x8 bf = *(const f16x8*)(b1 + rowb + (ks - 16) * 64);
          acc[ks & 3] = mfma16(wA[ks], bf, acc[ks & 3]);
        }
      }
      f32x4 a = (acc[0] + acc[1]) + (acc[2] + acc[3]);
      float ii = sigm(a[0] + bias[0]);
      float ff = sigm(a[1] + bias[1]);
      float gt = tanhx(a[2] + bias[2]);
      float oo = sigm(a[3] + bias[3]);
      c = ff * c + ii * gt;
      hval = oo * tanhx(c);
    }
    const bool produce = layer ? true : (s < T_SEQ);   // L1 emits zeros at s=0
    if (produce) {
      _Float16 hf = (_Float16)hval;
      unsigned short hu = __builtin_bit_cast(unsigned short, hf);
      int pv = __shfl_xor((int)hu, 16, 64);            // pair hidden j, j+1
      if ((kgrp & 1) == 0) {
        unsigned word = (unsigned)hu | (((unsigned)pv & 0xffffu) << 16);
        unsigned* dst = (layer ? h1g : h0g) + (s & 1) * 4096
                      + bcol * 256 + (hb >> 1) + (kgrp >> 1);
        st_u32(dst, word);
      }
    }
    asm volatile("s_waitcnt vmcnt(0)" ::: "memory");   // h complete at L3
    __syncthreads();
    if (tid == 0) st_u32(flg + w, (unsigned)(s + 1));
  }

  // ---- FC epilogue: out = relu([h0_T; h1_T] @ fc_w^T + fc_b), [128][1024]
  if (wid < 128) {
    const int rt = wid >> 4, ct = wid & 15;
    const int sg = rt & 3;
    const bool isH1 = (rt >= 4);
    const unsigned* src = ws + (isH1 ? H1_OFF_U32 : H0_OFF_U32)
                        + sg * 8192 + (isH1 ? 0 : 1) * 4096;  // h1_T slot0, h0_T slot1
    const unsigned* sfl = ws + FL_OFF_U32 + sg * 64;
    for (;;) {
      unsigned fl = ld_u32(sfl + lane);
      if (__all(fl >= (unsigned)STEPS)) break;
      if (++spins > 1000000u) break;
      __builtin_amdgcn_s_sleep(2);
    }
    asm volatile("" ::: "memory");
    #pragma unroll
    for (int it = 0; it < 16; ++it) {
      int i = tid + it * 256;
      sH[(i >> 8) * 260 + (i & 255)] = ld_u32(src + i);
    }
    __syncthreads();
    const int col = ct * 64 + wave * 16 + bcol;
    f32x4 a0 = {0,0,0,0}, a1 = {0,0,0,0};
    #pragma unroll
    for (int ks = 0; ks < 16; ++ks) {                  // K = 512
      f16x8 af = *(const f16x8*)((const char*)sH + rowb + ks * 64);
      f16x8 bf = cvt8(fcw + (size_t)col * H + ks * 32 + kgrp * 8);
      if (ks & 1) a1 = mfma16(af, bf, a1); else a0 = mfma16(af, bf, a0);
    }
    f32x4 a = a0 + a1;
    const float fb = fcb[col];
    #pragma unroll
    for (int r = 0; r < 4; ++r) {
      int row = rt * 16 + kgrp * 4 + r;
      float v = a[r] + fb;
      out[(size_t)row * 1024 + col] = v > 0.f ? v : 0.f;
    }
  }
}

extern "C" void kernel_launch(void* const* d_in, const int* in_sizes, int n_in,
                              void* d_out, int out_size, void* d_ws, size_t ws_size,
                              hipStream_t stream) {
  const float* x    = (const float*)d_in[0];
  const float* Wih0 = (const float*)d_in[1];
  const float* Whh0 = (const float*)d_in[2];
  const float* bih0 = (const float*)d_in[3];
  const float* bhh0 = (const float*)d_in[4];
  const float* Wih1 = (const float*)d_in[5];
  const float* Whh1 = (const float*)d_in[6];
  const float* bih1 = (const float*)d_in[7];
  const float* bhh1 = (const float*)d_in[8];
  const float* fcw  = (const float*)d_in[9];
  const float* fcb  = (const float*)d_in[10];
  (void)in_sizes; (void)n_in; (void)out_size; (void)ws_size;

  // zero h-state slots + flags every call (deterministic, graph-capture safe)
  hipMemsetAsync(d_ws, 0, WS_BYTES, stream);
  lstm_fused<<<dim3(256), dim3(256), 0, stream>>>(
      x, Wih0, Whh0, bih0, bhh0, Wih1, Whh1, bih1, bhh1, fcw, fcb,
      (float*)d_out, (unsigned*)d_ws);
}

// Round 2
// 4995.316 us; speedup vs baseline: 1.5306x; 1.5306x over previous
//
#include <hip/hip_runtime.h>

// ---------------------------------------------------------------------------
// Persistent fused 2-layer LSTM + FC for MI355X — tagged-data sync (v2).
//  - 256 WGs x 256 threads (1/CU), 4 independent batch-groups of 16.
//  - Layers pipelined: step s: L0 computes t=s, L1 computes t=s-1.
//  - Weights resident in VGPRs as fp16 MFMA A-fragments.
//  - h exchange: each element is u32 = fp16 | (tag<<16), written to a 3-slot
//    ring via agent-scope relaxed atomics; consumers poll data tags directly.
//    => ONE LLC round trip per step (no flags, no vmcnt drain, no hot lines).
//    Safety: skew<=1 step (entering s+1 requires all tag-s data), so writer
//    slot (s+1)%3 never collides with oldest reader slot (s-1)%3.
// ---------------------------------------------------------------------------

#define H      512
#define T_SEQ  1024
#define DIN    64
#define STEPS  1025

#define GRP_STRIDE_U32  49152   // 3 slots * 16384
#define SLOT_STRIDE_U32 16384   // [2 layers][16 batch][512 units] tagged u32
#define WS_BYTES        (4 * GRP_STRIDE_U32 * 4)

typedef _Float16 f16x8 __attribute__((ext_vector_type(8)));
typedef float    f32x4 __attribute__((ext_vector_type(4)));

__device__ __forceinline__ unsigned long long ld_u64(const unsigned long long* p) {
  return __hip_atomic_load((unsigned long long*)p, __ATOMIC_RELAXED, __HIP_MEMORY_SCOPE_AGENT);
}
__device__ __forceinline__ void st_u32(unsigned* p, unsigned v) {
  __hip_atomic_store(p, v, __ATOMIC_RELAXED, __HIP_MEMORY_SCOPE_AGENT);
}
__device__ __forceinline__ f16x8 pk8(float4 a, float4 b) {
  f16x8 r;
  r[0] = (_Float16)a.x; r[1] = (_Float16)a.y; r[2] = (_Float16)a.z; r[3] = (_Float16)a.w;
  r[4] = (_Float16)b.x; r[5] = (_Float16)b.y; r[6] = (_Float16)b.z; r[7] = (_Float16)b.w;
  return r;
}
__device__ __forceinline__ f16x8 cvt8(const float* p) {
  return pk8(*(const float4*)p, *(const float4*)(p + 4));
}
__device__ __forceinline__ f32x4 mfma16(f16x8 a, f16x8 b, f32x4 c) {
  return __builtin_amdgcn_mfma_f32_16x16x32_f16(a, b, c, 0, 0, 0);
}
__device__ __forceinline__ float rcpf_(float x) {
#if __has_builtin(__builtin_amdgcn_rcpf)
  return __builtin_amdgcn_rcpf(x);
#else
  return 1.0f / x;
#endif
}
__device__ __forceinline__ float sigm(float x) {
  x = fminf(fmaxf(x, -30.f), 30.f);
  return rcpf_(1.f + __expf(-x));
}
__device__ __forceinline__ float tanhx(float x) {
  x = fminf(fmaxf(x, -15.f), 15.f);
  float e = __expf(2.f * x);
  return (e - 1.f) * rcpf_(e + 1.f);
}

__global__ __launch_bounds__(256, 1)
void lstm_fused(const float* __restrict__ x,
                const float* __restrict__ Wih0, const float* __restrict__ Whh0,
                const float* __restrict__ bih0, const float* __restrict__ bhh0,
                const float* __restrict__ Wih1, const float* __restrict__ Whh1,
                const float* __restrict__ bih1, const float* __restrict__ bhh1,
                const float* __restrict__ fcw,  const float* __restrict__ fcb,
                float* __restrict__ out, unsigned* __restrict__ ws)
{
  // LDS: staged h payload tiles [2 layers][16 batch][256 u32-pairs + 4 pad]
  __shared__ unsigned sH[2 * 16 * 260];

  const int tid   = threadIdx.x;
  const int wid   = blockIdx.x;
  const int g     = wid >> 6;          // batch group 0..3
  const int w     = wid & 63;          // WG within group
  const int wave  = tid >> 6;
  const int lane  = tid & 63;
  const int layer = wave >> 1;         // waves 0,1 -> layer0 ; 2,3 -> layer1
  const int hb    = w * 8 + (wave & 1) * 4;  // hidden base of this wave (4 units)
  const int bcol  = lane & 15;         // batch-in-group (MFMA N col)
  const int kgrp  = lane >> 4;

  unsigned* gbase = ws + g * GRP_STRIDE_U32;

  // ---- gather resident W fragments (A operand; M rows = i,f,g,o interleaved
  //      per hidden unit so C/D lanes own one (hidden,batch) with 4 gate regs)
  const int src_m = lane & 15;
  const int grow  = (src_m & 3) * H + hb + (src_m >> 2);  // PyTorch gate-row
  f16x8 wA[32];
  if (layer == 0) {
    #pragma unroll
    for (int ks = 0; ks < 18; ++ks) {            // K = 64(x) + 512(h0) = 576
      int kk = ks * 32 + kgrp * 8;
      const float* p = (kk < DIN) ? (Wih0 + (size_t)grow * DIN + kk)
                                  : (Whh0 + (size_t)grow * H + (kk - DIN));
      wA[ks] = cvt8(p);
    }
  } else {
    #pragma unroll
    for (int ks = 0; ks < 32; ++ks) {            // K = 512(h0) + 512(h1) = 1024
      int kk = ks * 32 + kgrp * 8;
      const float* p = (kk < H) ? (Wih1 + (size_t)grow * H + kk)
                                : (Whh1 + (size_t)grow * H + (kk - H));
      wA[ks] = cvt8(p);
    }
  }
  const int hown = hb + kgrp;                    // hidden unit this lane owns
  float bias[4];
  {
    const float* bi = layer ? bih1 : bih0;
    const float* bh = layer ? bhh1 : bhh0;
    #pragma unroll
    for (int r = 0; r < 4; ++r) { int rr = r * H + hown; bias[r] = bi[rr] + bh[rr]; }
  }

  // zero LDS once: step 0 reads zeros as h_{-1}
  for (int i = tid; i < 2 * 16 * 260; i += 256) sH[i] = 0;
  __syncthreads();

  float c = 0.f;
  unsigned spins = 0;
  const int rowb = bcol * 1040 + kgrp * 16;      // LDS byte offset of B-frag row

  for (int s = 0; s < STEPS; ++s) {
    // x prefetch (raw; converted after stage so loads overlap the poll)
    float4 xr0 = {0,0,0,0}, xr1 = xr0, xr2 = xr0, xr3 = xr0;
    if (layer == 0) {
      int t = (s < T_SEQ) ? s : (T_SEQ - 1);
      const float* xp = x + ((size_t)((g * 16 + bcol) * T_SEQ + t)) * DIN + kgrp * 8;
      xr0 = *(const float4*)xp;        xr1 = *(const float4*)(xp + 4);
      xr2 = *(const float4*)(xp + 32); xr3 = *(const float4*)(xp + 36);
    }
    // poll+stage tagged h of generation s-1 from slot (s-1)%3
    if (s > 0) {
      const unsigned long long* src =
          (const unsigned long long*)(gbase + ((s - 1) % 3) * SLOT_STRIDE_U32);
      const unsigned want = (unsigned)s;
      unsigned long long v[32];
      #pragma unroll
      for (int i = 0; i < 32; ++i) v[i] = ld_u64(src + tid + i * 256);
      for (;;) {
        unsigned bad = 0;
        #pragma unroll
        for (int i = 0; i < 32; ++i) {
          unsigned lo = (unsigned)v[i], hi = (unsigned)(v[i] >> 32);
          if (((lo >> 16) ^ want) | ((hi >> 16) ^ want)) bad |= (1u << i);
        }
        if (!bad) break;
        if (++spins > 2000000u) break;           // bounded anti-hang guard
        #pragma unroll
        for (int i = 0; i < 32; ++i)
          if (bad & (1u << i)) v[i] = ld_u64(src + tid + i * 256);
      }
      #pragma unroll
      for (int i = 0; i < 32; ++i) {
        int j = tid + i * 256;                   // [2][16][256] u64 index
        unsigned payload = ((unsigned)v[i] & 0xffffu) | ((unsigned)(v[i] >> 32) << 16);
        sH[(j >> 12) * 4160 + ((j >> 8) & 15) * 260 + (j & 255)] = payload;
      }
    }
    __syncthreads();

    const bool active = layer ? (s > 0) : (s < T_SEQ);
    float hval = 0.f;
    if (active) {
      f32x4 acc[4] = {{0,0,0,0},{0,0,0,0},{0,0,0,0},{0,0,0,0}};
      const char* b0 = (const char*)sH;
      const char* b1 = (const char*)sH + 16640;
      if (layer == 0) {
        acc[0] = mfma16(wA[0], pk8(xr0, xr1), acc[0]);
        acc[1] = mfma16(wA[1], pk8(xr2, xr3), acc[1]);
        #pragma unroll
        for (int ks = 2; ks < 18; ++ks) {
          f16x8 bf = *(const f16x8*)(b0 + rowb + ks * 64 - 128);
          acc[ks & 3] = mfma16(wA[ks], bf, acc[ks & 3]);
        }
      } else {
        #pragma unroll
        for (int ks = 0; ks < 16; ++ks) {
          f16x8 bf = *(const f16x8*)(b0 + rowb + ks * 64);
          acc[ks & 3] = mfma16(wA[ks], bf, acc[ks & 3]);
        }
        #pragma unroll
        for (int ks = 16; ks < 32; ++ks) {
          f16x8 bf = *(const f16x8*)(b1 + rowb + (ks - 16) * 64);
          acc[ks & 3] = mfma16(wA[ks], bf, acc[ks & 3]);
        }
      }
      f32x4 a = (acc[0] + acc[1]) + (acc[2] + acc[3]);
      float ii = sigm(a[0] + bias[0]);
      float ff = sigm(a[1] + bias[1]);
      float gt = tanhx(a[2] + bias[2]);
      float oo = sigm(a[3] + bias[3]);
      c = ff * c + ii * gt;
      hval = oo * tanhx(c);
    }
    const bool produce = layer ? true : (s < T_SEQ);   // L1 emits zeros at s=0
    if (produce) {
      _Float16 hf = (_Float16)hval;
      unsigned hu = (unsigned)__builtin_bit_cast(unsigned short, hf);
      unsigned word = hu | ((unsigned)(s + 1) << 16);
      unsigned* dst = gbase + (s % 3) * SLOT_STRIDE_U32 + layer * 8192
                    + bcol * 512 + hown;
      st_u32(dst, word);                               // visible when polled
    }
    __syncthreads();                                   // protect sH reuse
  }

  // ---- FC epilogue: out = relu([h0_T; h1_T] @ fc_w^T + fc_b), [128][1024]
  if (wid < 128) {
    const int rt = wid >> 4, ct = wid & 15;
    const int sg = rt & 3;
    const bool isH1 = (rt >= 4);
    // h0_T = h0_{1023}: produced step 1023 -> slot 0, tag 1024, layer0 region
    // h1_T = h1_{1023}: produced step 1024 -> slot 1, tag 1025, layer1 region
    const unsigned want = isH1 ? (unsigned)(STEPS + 0) : (unsigned)(STEPS - 1);
    const int     slot  = isH1 ? 1 : 0;
    const unsigned long long* src =
        (const unsigned long long*)(ws + sg * GRP_STRIDE_U32
                                    + slot * SLOT_STRIDE_U32 + (isH1 ? 8192 : 0));
    unsigned long long v[16];
    #pragma unroll
    for (int i = 0; i < 16; ++i) v[i] = ld_u64(src + tid + i * 256);
    for (;;) {
      unsigned bad = 0;
      #pragma unroll
      for (int i = 0; i < 16; ++i) {
        unsigned lo = (unsigned)v[i], hi = (unsigned)(v[i] >> 32);
        if (((lo >> 16) ^ want) | ((hi >> 16) ^ want)) bad |= (1u << i);
      }
      if (!bad) break;
      if (++spins > 2000000u) break;
      #pragma unroll
      for (int i = 0; i < 16; ++i)
        if (bad & (1u << i)) v[i] = ld_u64(src + tid + i * 256);
    }
    #pragma unroll
    for (int i = 0; i < 16; ++i) {
      int j = tid + i * 256;                       // [16][256] u64 index
      unsigned payload = ((unsigned)v[i] & 0xffffu) | ((unsigned)(v[i] >> 32) << 16);
      sH[(j >> 8) * 260 + (j & 255)] = payload;
    }
    __syncthreads();
    const int col = ct * 64 + wave * 16 + bcol;
    f32x4 a0 = {0,0,0,0}, a1 = {0,0,0,0};
    #pragma unroll
    for (int ks = 0; ks < 16; ++ks) {              // K = 512
      f16x8 af = *(const f16x8*)((const char*)sH + rowb + ks * 64);
      f16x8 bf = cvt8(fcw + (size_t)col * H + ks * 32 + kgrp * 8);
      if (ks & 1) a1 = mfma16(af, bf, a1); else a0 = mfma16(af, bf, a0);
    }
    f32x4 a = a0 + a1;
    const float fb = fcb[col];
    #pragma unroll
    for (int r = 0; r < 4; ++r) {
      int row = rt * 16 + kgrp * 4 + r;
      float v2 = a[r] + fb;
      out[(size_t)row * 1024 + col] = v2 > 0.f ? v2 : 0.f;
    }
  }
}

extern "C" void kernel_launch(void* const* d_in, const int* in_sizes, int n_in,
                              void* d_out, int out_size, void* d_ws, size_t ws_size,
                              hipStream_t stream) {
  const float* x    = (const float*)d_in[0];
  const float* Wih0 = (const float*)d_in[1];
  const float* Whh0 = (const float*)d_in[2];
  const float* bih0 = (const float*)d_in[3];
  const float* bhh0 = (const float*)d_in[4];
  const float* Wih1 = (const float*)d_in[5];
  const float* Whh1 = (const float*)d_in[6];
  const float* bih1 = (const float*)d_in[7];
  const float* bhh1 = (const float*)d_in[8];
  const float* fcw  = (const float*)d_in[9];
  const float* fcb  = (const float*)d_in[10];
  (void)in_sizes; (void)n_in; (void)out_size; (void)ws_size;

  // zero tag space every call (tag 0 never matches any wanted tag >= 1)
  hipMemsetAsync(d_ws, 0, WS_BYTES, stream);
  lstm_fused<<<dim3(256), dim3(256), 0, stream>>>(
      x, Wih0, Whh0, bih0, bhh0, Wih1, Whh1, bih1, bhh1, fcw, fcb,
      (float*)d_out, (unsigned*)d_ws);
}